// Round 7
// baseline (231.339 us; speedup 1.0000x reference)
//
#include <hip/hip_runtime.h>
#include <stdint.h>

// Problem geometry (fixed by the reference):
//   probs: (B=2, C=2, D=32, H=512, W=512) fp32
//   mask : (B=2, D=32, H=512, W=512)      int32, values {0,1,2}; 2 = ignore -> class 0
// Output: scalar fp32 = mean over all B*C*D*H*W of (probs - onehot)^2
static constexpr long long DHW       = 32LL * 512 * 512;   // 8388608 = 1<<23
static constexpr long long N_SPATIAL = 2LL * DHW;          // 16777216
static constexpr long long N_TOTAL   = 2LL * N_SPATIAL;    // 33554432

static constexpr int GRID   = 1024;
static constexpr int BLOCK  = 256;                          // 4 waves
static constexpr int ROUNDS = 16;
static constexpr long long CHUNKS  = N_SPATIAL / 4;         // 4194304 float4 chunks
static constexpr long long RSTRIDE = (long long)GRID * BLOCK;  // 262144 chunks/round
static_assert(CHUNKS == (long long)ROUNDS * RSTRIDE, "exact trip count");

typedef float fx4 __attribute__((ext_vector_type(4)));
typedef int   ix4 __attribute__((ext_vector_type(4)));

// VMEM->LDS DMA, 16 B per lane. LDS dest is wave-uniform base + lane*16.
__device__ __forceinline__ void stage16(const void* g, void* lds) {
    __builtin_amdgcn_global_load_lds(
        (const __attribute__((address_space(1))) void*)g,
        (__attribute__((address_space(3))) void*)lds,
        16, 0, 0);
}

__global__ __launch_bounds__(BLOCK) void betti_mse_partial(const float* __restrict__ probs,
                                                           const int*   __restrict__ mask,
                                                           double*      __restrict__ partial) {
    // Per-wave private double-buffered staging: 3 streams x 1 KB per wave per
    // round. No __syncthreads anywhere — each wave consumes only its own
    // segment, ordered by explicit s_waitcnt vmcnt(N).
    __shared__ float lp0[2][BLOCK * 4];   // 8 KB
    __shared__ float lp1[2][BLOCK * 4];   // 8 KB
    __shared__ int   lm [2][BLOCK * 4];   // 8 KB

    const int tid  = threadIdx.x;
    const int wseg = (tid >> 6) << 8;     // wave segment start, in elements (wid*256)

    float a0 = 0.0f, a1 = 0.0f;

    auto stage = [&](int buf, int r) {
        const long long v    = (long long)r * RSTRIDE + (long long)blockIdx.x * BLOCK + tid;
        const long long s    = v << 2;            // spatial flat index
        const long long b    = s >> 23;           // s / DHW
        const long long base = (b << 24) + (s & (DHW - 1));   // b*C*DHW + rest (c=0)
        stage16(probs + base,       &lp0[buf][wseg]);
        stage16(probs + base + DHW, &lp1[buf][wseg]);
        stage16(mask + s,           &lm [buf][wseg]);
    };

    auto consume = [&](int buf) {
        const fx4 p0 = *reinterpret_cast<const fx4*>(&lp0[buf][tid << 2]);
        const fx4 p1 = *reinterpret_cast<const fx4*>(&lp1[buf][tid << 2]);
        const ix4 m  = *reinterpret_cast<const ix4*>(&lm [buf][tid << 2]);
        const float t0 = (m.x == 1) ? 1.0f : 0.0f;
        const float t1 = (m.y == 1) ? 1.0f : 0.0f;
        const float t2 = (m.z == 1) ? 1.0f : 0.0f;
        const float t3 = (m.w == 1) ? 1.0f : 0.0f;
        float d;
        d = p0.x - (1.0f - t0); a0 += d * d;
        d = p0.y - (1.0f - t1); a1 += d * d;
        d = p0.z - (1.0f - t2); a0 += d * d;
        d = p0.w - (1.0f - t3); a1 += d * d;
        d = p1.x - t0;          a0 += d * d;
        d = p1.y - t1;          a1 += d * d;
        d = p1.z - t2;          a0 += d * d;
        d = p1.w - t3;          a1 += d * d;
    };

    stage(0, 0);                                   // prologue prefetch
    for (int r = 0; r < ROUNDS - 1; ++r) {
        stage((r + 1) & 1, r + 1);                 // prefetch next round (3 loads)
        // wait for round r's 3 loads (oldest); round r+1's 3 stay in flight.
        // simm16: vmcnt=3, expcnt=7 (ignore), lgkmcnt=15 (ignore) -> 0x0F73
        __builtin_amdgcn_s_waitcnt(0x0F73);
        __asm__ __volatile__("" ::: "memory");
        consume(r & 1);
        __asm__ __volatile__("" ::: "memory");
    }
    __builtin_amdgcn_s_waitcnt(0x0F70);            // vmcnt(0)
    __asm__ __volatile__("" ::: "memory");
    consume((ROUNDS - 1) & 1);

    float local = a0 + a1;
    #pragma unroll
    for (int off = 32; off > 0; off >>= 1)
        local += __shfl_down(local, off, 64);

    __shared__ float wsum[4];
    const int lane = tid & 63;
    const int wid  = tid >> 6;
    if (lane == 0) wsum[wid] = local;
    __syncthreads();
    if (tid == 0)
        partial[blockIdx.x] = (double)(wsum[0] + wsum[1] + wsum[2] + wsum[3]);
}

__global__ __launch_bounds__(BLOCK) void betti_mse_final(const double* __restrict__ partial,
                                                         float* __restrict__ out) {
    double local = 0.0;
    #pragma unroll
    for (int k = 0; k < GRID / BLOCK; ++k)   // 4 partials per thread
        local += partial[threadIdx.x + k * BLOCK];

    #pragma unroll
    for (int off = 32; off > 0; off >>= 1)
        local += __shfl_down(local, off, 64);

    __shared__ double wsum[4];
    const int lane = threadIdx.x & 63;
    const int wid  = threadIdx.x >> 6;
    if (lane == 0) wsum[wid] = local;
    __syncthreads();
    if (threadIdx.x == 0)
        out[0] = (float)((wsum[0] + wsum[1] + wsum[2] + wsum[3]) / (double)N_TOTAL);
}

extern "C" void kernel_launch(void* const* d_in, const int* in_sizes, int n_in,
                              void* d_out, int out_size, void* d_ws, size_t ws_size,
                              hipStream_t stream) {
    const float* probs   = (const float*)d_in[0];
    const int*   mask    = (const int*)d_in[1];
    float*       out     = (float*)d_out;
    double*      partial = (double*)d_ws;   // GRID doubles = 8 KB scratch

    betti_mse_partial<<<GRID, BLOCK, 0, stream>>>(probs, mask, partial);
    betti_mse_final<<<1, BLOCK, 0, stream>>>(partial, out);
}

// Round 8
// 221.883 us; speedup vs baseline: 1.0426x; 1.0426x over previous
//
#include <hip/hip_runtime.h>

// Problem geometry (fixed by the reference):
//   probs: (B=2, C=2, D=32, H=512, W=512) fp32
//   mask : (B=2, D=32, H=512, W=512)      int32, values {0,1,2}; 2 = ignore -> class 0
// Output: scalar fp32 = mean over all B*C*D*H*W of (probs - onehot)^2
static constexpr long long DHW       = 32LL * 512 * 512;   // 8388608 = 1<<23
static constexpr long long N_SPATIAL = 2LL * DHW;          // 16777216
static constexpr long long N_TOTAL   = 2LL * N_SPATIAL;    // 33554432

static constexpr int GRID   = 2048;   // 32 waves/CU — max TLP over per-round waits
static constexpr int BLOCK  = 256;    // 4 waves
static constexpr int ROUNDS = 8;
static constexpr long long CHUNKS  = N_SPATIAL / 4;            // 4194304 float4 chunks
static constexpr long long RSTRIDE = (long long)GRID * BLOCK;  // 524288 chunks/round
static_assert(CHUNKS == (long long)ROUNDS * RSTRIDE, "exact trip count");

typedef float fx4 __attribute__((ext_vector_type(4)));
typedef int   ix4 __attribute__((ext_vector_type(4)));

// VMEM->LDS DMA, 16 B/lane, wave-uniform LDS base + lane*16.
__device__ __forceinline__ void stage16(const void* g, void* lds) {
    __builtin_amdgcn_global_load_lds(
        (const __attribute__((address_space(1))) void*)g,
        (__attribute__((address_space(3))) void*)lds,
        16, 0, 0);
}

__global__ __launch_bounds__(BLOCK) void betti_mse_partial(const float* __restrict__ probs,
                                                           const int*   __restrict__ mask,
                                                           double*      __restrict__ partial) {
    // HYBRID read paths: probs (2/3 of bytes) via nontemporal VGPR loads,
    // mask (1/3) via global_load_lds DMA into per-wave-private double buffers.
    // Theory: the two return paths have separate per-CU tracking resources.
    __shared__ int lm[2][BLOCK * 4];   // 8 KB: 2 bufs x 4 waves x 1 KB

    const int tid  = threadIdx.x;
    const int wseg = (tid >> 6) << 8;  // wave's segment start (ints): wid*256

    auto sidx = [&](int r) -> long long {
        return ((long long)r * RSTRIDE + (long long)blockIdx.x * BLOCK + tid) << 2;
    };
    auto probs_base = [&](long long s) -> long long {
        return ((s >> 23) << 24) + (s & (DHW - 1));   // b*C*DHW + rest (c=0)
    };

    float a0 = 0.0f, a1 = 0.0f;
    fx4 p0c, p1c, p0n, p1n;

    // Prologue: round 0 in flight (order: mask DMA, then probs NT).
    {
        const long long s = sidx(0);
        stage16(mask + s, &lm[0][wseg]);
        const long long base = probs_base(s);
        p0c = __builtin_nontemporal_load(reinterpret_cast<const fx4*>(probs + base));
        p1c = __builtin_nontemporal_load(reinterpret_cast<const fx4*>(probs + base + DHW));
    }

    for (int r = 0; r < ROUNDS; ++r) {
        if (r + 1 < ROUNDS) {
            const long long s = sidx(r + 1);
            stage16(mask + s, &lm[(r + 1) & 1][wseg]);
            const long long base = probs_base(s);
            p0n = __builtin_nontemporal_load(reinterpret_cast<const fx4*>(probs + base));
            p1n = __builtin_nontemporal_load(reinterpret_cast<const fx4*>(probs + base + DHW));
        }
        __asm__ __volatile__("" ::: "memory");
        // r's trio are the oldest outstanding; r+1's 3 newest may stay in flight.
        // simm16: vmcnt=3 -> 0x0F73; last round drain all -> vmcnt=0 -> 0x0F70.
        if (r + 1 < ROUNDS) __builtin_amdgcn_s_waitcnt(0x0F73);
        else                __builtin_amdgcn_s_waitcnt(0x0F70);
        __asm__ __volatile__("" ::: "memory");

        const ix4 m = *reinterpret_cast<const ix4*>(&lm[r & 1][tid << 2]);
        const float t0 = (m.x == 1) ? 1.0f : 0.0f;
        const float t1 = (m.y == 1) ? 1.0f : 0.0f;
        const float t2 = (m.z == 1) ? 1.0f : 0.0f;
        const float t3 = (m.w == 1) ? 1.0f : 0.0f;
        float d;
        d = p0c.x - (1.0f - t0); a0 += d * d;
        d = p0c.y - (1.0f - t1); a1 += d * d;
        d = p0c.z - (1.0f - t2); a0 += d * d;
        d = p0c.w - (1.0f - t3); a1 += d * d;
        d = p1c.x - t0;          a0 += d * d;
        d = p1c.y - t1;          a1 += d * d;
        d = p1c.z - t2;          a0 += d * d;
        d = p1c.w - t3;          a1 += d * d;

        p0c = p0n;
        p1c = p1n;
    }

    float local = a0 + a1;
    #pragma unroll
    for (int off = 32; off > 0; off >>= 1)
        local += __shfl_down(local, off, 64);

    __shared__ float wsum[4];
    const int lane = tid & 63;
    const int wid  = tid >> 6;
    if (lane == 0) wsum[wid] = local;
    __syncthreads();
    if (tid == 0)
        partial[blockIdx.x] = (double)(wsum[0] + wsum[1] + wsum[2] + wsum[3]);
}

__global__ __launch_bounds__(BLOCK) void betti_mse_final(const double* __restrict__ partial,
                                                         float* __restrict__ out) {
    double local = 0.0;
    #pragma unroll
    for (int k = 0; k < GRID / BLOCK; ++k)   // 8 partials per thread
        local += partial[threadIdx.x + k * BLOCK];

    #pragma unroll
    for (int off = 32; off > 0; off >>= 1)
        local += __shfl_down(local, off, 64);

    __shared__ double wsum[4];
    const int lane = threadIdx.x & 63;
    const int wid  = threadIdx.x >> 6;
    if (lane == 0) wsum[wid] = local;
    __syncthreads();
    if (threadIdx.x == 0)
        out[0] = (float)((wsum[0] + wsum[1] + wsum[2] + wsum[3]) / (double)N_TOTAL);
}

extern "C" void kernel_launch(void* const* d_in, const int* in_sizes, int n_in,
                              void* d_out, int out_size, void* d_ws, size_t ws_size,
                              hipStream_t stream) {
    const float* probs   = (const float*)d_in[0];
    const int*   mask    = (const int*)d_in[1];
    float*       out     = (float*)d_out;
    double*      partial = (double*)d_ws;   // GRID doubles = 16 KB scratch

    betti_mse_partial<<<GRID, BLOCK, 0, stream>>>(probs, mask, partial);
    betti_mse_final<<<1, BLOCK, 0, stream>>>(partial, out);
}

// Round 9
// 216.833 us; speedup vs baseline: 1.0669x; 1.0233x over previous
//
#include <hip/hip_runtime.h>

// Problem geometry (fixed by the reference):
//   probs: (B=2, C=2, D=32, H=512, W=512) fp32
//   mask : (B=2, D=32, H=512, W=512)      int32, values {0,1,2}; 2 = ignore -> class 0
// Output: scalar fp32 = mean over all B*C*D*H*W of (probs - onehot)^2
//
// Final form (R5 config): pure-read streaming reduction, all three streams via
// NONTEMPORAL dwordx4 loads (nt lifts the cache-allocation throttle on the
// read-return path: 78 -> 57 us kernel, R4). Further levers measured neutral
// or negative: software MLP depth (R2), waves/CU (R5), global_load_lds DMA
// (R6), hybrid NT+DMA (R7). Effective read BW ~3.5 TB/s = machine read
// ceiling (copy read-side ~3.15 TB/s; writes-only 6.9 TB/s).
static constexpr long long DHW       = 32LL * 512 * 512;   // 8388608 = 1<<23
static constexpr long long N_SPATIAL = 2LL * DHW;          // 16777216
static constexpr long long N_TOTAL   = 2LL * N_SPATIAL;    // 33554432

static constexpr int GRID  = 1024;   // 4 blocks/CU x 4 waves = 16 waves/CU
static constexpr int BLOCK = 256;
static constexpr int ITERS = 16;     // 48 NT loads (48 KB) in flight per wave
static constexpr long long NVEC   = N_SPATIAL / 4;             // 4194304 float4 chunks
static constexpr long long STRIDE = (long long)GRID * BLOCK;   // 262144
static_assert(NVEC == (long long)ITERS * STRIDE, "exact trip count");

// Native clang vector types — required by __builtin_nontemporal_load
// (HIP_vector_type float4/int4 are structs and are rejected).
typedef float fx4 __attribute__((ext_vector_type(4)));
typedef int   ix4 __attribute__((ext_vector_type(4)));

__global__ __launch_bounds__(BLOCK) void betti_mse_partial(const float* __restrict__ probs,
                                                           const int*   __restrict__ mask,
                                                           double*      __restrict__ partial) {
    const long long v0 = (long long)blockIdx.x * BLOCK + threadIdx.x;

    fx4 P0[ITERS], P1[ITERS];
    ix4 M[ITERS];
    #pragma unroll
    for (int i = 0; i < ITERS; ++i) {
        const long long s    = (v0 + (long long)i * STRIDE) << 2;  // spatial flat idx
        const long long b    = s >> 23;                            // s / DHW
        const long long rest = s & (DHW - 1);                      // s % DHW
        const long long base = (b << 24) + rest;                   // b*C*DHW + rest
        P0[i] = __builtin_nontemporal_load(reinterpret_cast<const fx4*>(probs + base));
        P1[i] = __builtin_nontemporal_load(reinterpret_cast<const fx4*>(probs + base + DHW));
        M[i]  = __builtin_nontemporal_load(reinterpret_cast<const ix4*>(mask + s));
    }

    float acc0 = 0.0f, acc1 = 0.0f;
    #pragma unroll
    for (int i = 0; i < ITERS; ++i) {
        const float t0 = (M[i].x == 1) ? 1.0f : 0.0f;
        const float t1 = (M[i].y == 1) ? 1.0f : 0.0f;
        const float t2 = (M[i].z == 1) ? 1.0f : 0.0f;
        const float t3 = (M[i].w == 1) ? 1.0f : 0.0f;
        float d;
        d = P0[i].x - (1.0f - t0); acc0 += d * d;
        d = P0[i].y - (1.0f - t1); acc1 += d * d;
        d = P0[i].z - (1.0f - t2); acc0 += d * d;
        d = P0[i].w - (1.0f - t3); acc1 += d * d;
        d = P1[i].x - t0;          acc0 += d * d;
        d = P1[i].y - t1;          acc1 += d * d;
        d = P1[i].z - t2;          acc0 += d * d;
        d = P1[i].w - t3;          acc1 += d * d;
    }
    float local = acc0 + acc1;

    #pragma unroll
    for (int off = 32; off > 0; off >>= 1)
        local += __shfl_down(local, off, 64);

    __shared__ float wsum[4];
    const int lane = threadIdx.x & 63;
    const int wid  = threadIdx.x >> 6;
    if (lane == 0) wsum[wid] = local;
    __syncthreads();
    if (threadIdx.x == 0)
        partial[blockIdx.x] = (double)(wsum[0] + wsum[1] + wsum[2] + wsum[3]);
}

__global__ __launch_bounds__(BLOCK) void betti_mse_final(const double* __restrict__ partial,
                                                         float* __restrict__ out) {
    double local = 0.0;
    #pragma unroll
    for (int k = 0; k < GRID / BLOCK; ++k)   // 4 partials per thread
        local += partial[threadIdx.x + k * BLOCK];

    #pragma unroll
    for (int off = 32; off > 0; off >>= 1)
        local += __shfl_down(local, off, 64);

    __shared__ double wsum[4];
    const int lane = threadIdx.x & 63;
    const int wid  = threadIdx.x >> 6;
    if (lane == 0) wsum[wid] = local;
    __syncthreads();
    if (threadIdx.x == 0)
        out[0] = (float)((wsum[0] + wsum[1] + wsum[2] + wsum[3]) / (double)N_TOTAL);
}

extern "C" void kernel_launch(void* const* d_in, const int* in_sizes, int n_in,
                              void* d_out, int out_size, void* d_ws, size_t ws_size,
                              hipStream_t stream) {
    const float* probs   = (const float*)d_in[0];
    const int*   mask    = (const int*)d_in[1];
    float*       out     = (float*)d_out;
    double*      partial = (double*)d_ws;   // GRID doubles = 8 KB scratch

    betti_mse_partial<<<GRID, BLOCK, 0, stream>>>(probs, mask, partial);
    betti_mse_final<<<1, BLOCK, 0, stream>>>(partial, out);
}